// Round 1
// baseline (197.730 us; speedup 1.0000x reference)
//
#include <hip/hip_runtime.h>
#include <math.h>

#define NT    512
#define MM    2048
#define CC    64
#define RH    4
#define NIF   461
#define INS   512
#define EPSN  1e-6f

typedef unsigned long long u64;

__global__ __launch_bounds__(NT) void dnc_kernel(
    const float* __restrict__ xi, const float* __restrict__ W,
    const float* __restrict__ gamma, const float* __restrict__ beta,
    const float* __restrict__ memory, const float* __restrict__ read_w,
    const float* __restrict__ write_w, const float* __restrict__ usage,
    float* __restrict__ out)
{
  const int b    = blockIdx.x;
  const int tid  = threadIdx.x;
  const int lane = tid & 63;
  const int wid  = tid >> 6;

  // ---- LDS carve (≈61.5 KB total, aliased) ----
  __shared__ __align__(16) float sU1[4352];      // xi/itf/act -> scanA/scanB -> chunk[64][68]
  __shared__ __align__(16) u64   sKeys[2048];    // sort keys -> ww (first 8KB) + red (second 8KB)
  __shared__ __align__(16) float sWcw[2048];
  __shared__ __align__(16) float sMrw[2048];
  __shared__ __align__(16) float sAlloc[2048];
  __shared__ __align__(16) float sE[4*68];
  __shared__ __align__(16) float sRk[4*64];
  __shared__ __align__(16) float sWkv[64];
  __shared__ __align__(16) float sEr[64];
  __shared__ __align__(16) float sWv[64];
  __shared__ float sMisc[16];
  __shared__ float sRed[24];
  __shared__ float sHm[4], sHs[4], sHsc[4];

  float* s_xi  = sU1;
  float* s_itf = sU1 + 512;
  float* s_act = sU1 + 1024;

  // ---- load xi row ----
  s_xi[tid] = xi[(size_t)b*INS + tid];
  __syncthreads();

  // ---- itf = xi @ W^T (wave-cooperative per column, coalesced 2KB/row) ----
  {
    const float4 x0 = ((const float4*)s_xi)[lane*2];
    const float4 x1 = ((const float4*)s_xi)[lane*2+1];
    for (int col = wid; col < NIF; col += 8) {
      const float4* Wr = (const float4*)(W + (size_t)col*INS);
      float4 a0 = Wr[lane*2], a1 = Wr[lane*2+1];
      float p = a0.x*x0.x + a0.y*x0.y + a0.z*x0.z + a0.w*x0.w
              + a1.x*x1.x + a1.y*x1.y + a1.z*x1.z + a1.w*x1.w;
      #pragma unroll
      for (int off=1; off<64; off<<=1) p += __shfl_xor(p, off);
      if (lane==0) s_itf[col] = p;
    }
  }
  __syncthreads();

  // ---- GroupNorm over 461 channels ----
  {
    float v = (tid < NIF) ? s_itf[tid] : 0.f;
    float s = v, q = v*v;
    #pragma unroll
    for (int off=1; off<64; off<<=1) { s += __shfl_xor(s,off); q += __shfl_xor(q,off); }
    if (lane==0){ sRed[wid] = s; sRed[8+wid] = q; }
    __syncthreads();
    if (tid==0){
      float ts=0.f, tq=0.f;
      for (int i=0;i<8;i++){ ts+=sRed[i]; tq+=sRed[8+i]; }
      float mean = ts/(float)NIF;
      float var  = tq/(float)NIF - mean*mean;
      sRed[16]=mean; sRed[17]=rsqrtf(var+1e-5f);
    }
    __syncthreads();
    float mean = sRed[16], rstd = sRed[17];
    if (tid < NIF) {
      float g = (s_itf[tid]-mean)*rstd*gamma[tid] + beta[tid];
      float a;
      if      (tid < 256) a = tanhf(g);
      else if (tid < 260) a = fmaxf(g,0.f) + log1pf(expf(-fabsf(g)));   // softplus
      else if (tid < 324) a = tanhf(g);
      else if (tid ==324) a = fmaxf(g,0.f) + log1pf(expf(-fabsf(g)));
      else if (tid < 389) a = 1.f/(1.f+expf(-g));                       // erase
      else if (tid < 453) a = tanhf(g);                                 // write vec
      else if (tid < 457) a = 1.f/(1.f+expf(-g));                       // free gates
      else if (tid < 460) a = g;                                        // alloc gate (raw)
      else                a = 1.f/(1.f+expf(-g));                       // write gate
      s_act[tid] = a;
    }
  }
  __syncthreads();

  // ---- fold keys with norm+strength; extract small gates ----
  if (wid < 4) {
    float t = s_act[wid*64 + lane];
    float q = t*t;
    #pragma unroll
    for (int off=1; off<64; off<<=1) q += __shfl_xor(q,off);
    float scl = s_act[256+wid] / (sqrtf(q) + EPSN);
    sRk[wid*64+lane] = t*scl;
  } else if (wid == 4) {
    float t = s_act[260+lane];
    float q = t*t;
    #pragma unroll
    for (int off=1; off<64; off<<=1) q += __shfl_xor(q,off);
    float scl = s_act[324] / (sqrtf(q) + EPSN);
    sWkv[lane] = t*scl;
  } else if (wid == 5) {
    sEr[lane] = s_act[325+lane];
    sWv[lane] = s_act[389+lane];
  } else if (wid == 6 && lane == 0) {
    sMisc[0]=s_act[453]; sMisc[1]=s_act[454]; sMisc[2]=s_act[455]; sMisc[3]=s_act[456];
    float a0=s_act[457], a1=s_act[458], a2=s_act[459];
    float mx = fmaxf(a0, fmaxf(a1,a2));
    float e0=expf(a0-mx), e1=expf(a1-mx), e2=expf(a2-mx);
    float is = 1.f/(e0+e1+e2);
    sMisc[4]=e0*is; sMisc[5]=e1*is; sMisc[6]=e2*is;
    sMisc[7]=s_act[460];
  }
  __syncthreads();

  // ---- usage update, mean read weights, sort keys ----
  {
    const float4* us4 = (const float4*)(usage   + (size_t)b*MM);
    const float4* wr4 = (const float4*)(write_w + (size_t)b*MM);
    const float4* rw4 = (const float4*)(read_w  + (size_t)b*RH*MM);
    const float fg0=sMisc[0], fg1=sMisc[1], fg2=sMisc[2], fg3=sMisc[3];
    float4 u = us4[tid], w = wr4[tid];
    float4 r0 = rw4[tid], r1 = rw4[512+tid], r2 = rw4[1024+tid], r3 = rw4[1536+tid];
    float4 mr;
    mr.x = 0.25f*(r0.x+r1.x+r2.x+r3.x);
    mr.y = 0.25f*(r0.y+r1.y+r2.y+r3.y);
    mr.z = 0.25f*(r0.z+r1.z+r2.z+r3.z);
    mr.w = 0.25f*(r0.w+r1.w+r2.w+r3.w);
    ((float4*)sMrw)[tid] = mr;
    const int base = tid*4;
    #define MK(comp, off)                                                      \
    { float uu  = u.comp + (1.f-u.comp)*w.comp;                                \
      float psi = (1.f-fg0*r0.comp)*(1.f-fg1*r1.comp)*(1.f-fg2*r2.comp)*(1.f-fg3*r3.comp); \
      float u2v = 1e-6f + (1.f-1e-6f)*(uu*psi);                                \
      sKeys[base+off] = ((u64)__float_as_uint(u2v)<<32) | (unsigned)(base+off); }
    MK(x,0) MK(y,1) MK(z,2) MK(w,3)
    #undef MK
  }

  // ---- Pass A: write-key cosine scores over memory ----
  {
    const int l16 = tid & 15, rowg = tid >> 4;
    const float4* mem4 = (const float4*)(memory + (size_t)b*MM*CC);
    const float4 wk4 = ((const float4*)sWkv)[l16];
    #pragma unroll 4
    for (int m = rowg; m < MM; m += 32) {
      float4 v = mem4[m*16 + l16];
      float d = v.x*wk4.x + v.y*wk4.y + v.z*wk4.z + v.w*wk4.w;
      float q = v.x*v.x + v.y*v.y + v.z*v.z + v.w*v.w;
      #pragma unroll
      for (int off=1; off<16; off<<=1){ d += __shfl_xor(d,off); q += __shfl_xor(q,off); }
      if (l16==0) sWcw[m] = d / (sqrtf(q)+EPSN);
    }
  }
  __syncthreads();

  // ---- softmax over 2048 write scores ----
  {
    float4 f = ((const float4*)sWcw)[tid];
    float lm = fmaxf(fmaxf(f.x,f.y), fmaxf(f.z,f.w));
    #pragma unroll
    for (int off=1; off<64; off<<=1) lm = fmaxf(lm, __shfl_xor(lm,off));
    if (lane==0) sRed[wid] = lm;
    __syncthreads();
    if (tid==0){ float mx=sRed[0]; for(int i=1;i<8;i++) mx=fmaxf(mx,sRed[i]); sRed[16]=mx; }
    __syncthreads();
    float mx = sRed[16];
    float e0=expf(f.x-mx), e1=expf(f.y-mx), e2=expf(f.z-mx), e3=expf(f.w-mx);
    float ls = e0+e1+e2+e3;
    #pragma unroll
    for (int off=1; off<64; off<<=1) ls += __shfl_xor(ls,off);
    if (lane==0) sRed[8+wid] = ls;
    __syncthreads();
    if (tid==0){ float s=0.f; for(int i=0;i<8;i++) s+=sRed[8+i]; sRed[17]=1.f/s; }
    __syncthreads();
    float is = sRed[17];
    float4 o; o.x=e0*is; o.y=e1*is; o.z=e2*is; o.w=e3*is;
    ((float4*)sWcw)[tid] = o;
  }

  // ---- bitonic sort of (u2,index) keys, stable ascending ----
  for (int k = 2; k <= MM; k <<= 1) {
    for (int j = k >> 1; j > 0; j >>= 1) {
      __syncthreads();
      for (int i = tid; i < MM; i += NT) {
        int ixj = i ^ j;
        if (ixj > i) {
          u64 a = sKeys[i], c = sKeys[ixj];
          bool up = ((i & k) == 0);
          if ((a > c) == up) { sKeys[i] = c; sKeys[ixj] = a; }
        }
      }
    }
  }
  __syncthreads();

  // ---- exclusive cumprod (Hillis-Steele) + allocation scatter ----
  {
    float* scanA = sU1;
    float* scanB = sU1 + 2048;
    for (int i = tid; i < MM; i += NT)
      scanA[i] = __uint_as_float((unsigned)(sKeys[i]>>32));
    __syncthreads();
    float* src = scanA; float* dst = scanB;
    for (int d = 1; d < MM; d <<= 1) {
      for (int i = tid; i < MM; i += NT) {
        float v = src[i];
        if (i >= d) v *= src[i-d];
        dst[i] = v;
      }
      __syncthreads();
      float* t = src; src = dst; dst = t;
    }
    for (int i = tid; i < MM; i += NT) {
      u64 kk = sKeys[i];
      float su  = __uint_as_float((unsigned)(kk>>32));
      unsigned idx = (unsigned)(kk & 0xFFFFFFFFu);
      float cp = (i>0) ? src[i-1] : 1.f;
      sAlloc[idx] = (1.f - su)*cp;
    }
  }
  __syncthreads();

  // ---- write weighting ww (reuse keys region) ----
  float* sWwF = (float*)sKeys;
  {
    const float ag0=sMisc[4], ag1=sMisc[5], ag2=sMisc[6], wg=sMisc[7];
    for (int i = tid; i < MM; i += NT)
      sWwF[i] = wg*(ag0*sMrw[i] + ag1*sAlloc[i] + ag2*sWcw[i]);
  }
  if (tid < 4){ sHm[tid] = -INFINITY; sHs[tid] = 0.f; }
  __syncthreads();

  // ---- Pass B: erase/write memory, read-key scores, online-softmax read ----
  {
    const int l16 = tid & 15, rowg = tid >> 4;
    const int rq = (tid >> 4) & 3, cq = tid & 15, pg = wid;
    const float4* mem4 = (const float4*)(memory + (size_t)b*MM*CC);
    const float4 er4 = ((const float4*)sEr)[l16];
    const float4 wv4 = ((const float4*)sWv)[l16];
    const float4 k0 = ((const float4*)sRk)[     l16];
    const float4 k1 = ((const float4*)sRk)[16 + l16];
    const float4 k2 = ((const float4*)sRk)[32 + l16];
    const float4 k3 = ((const float4*)sRk)[48 + l16];
    float* chunk = sU1;   // [64][68]
    float4 acc; acc.x=acc.y=acc.z=acc.w=0.f;

    for (int ch = 0; ch < 32; ++ch) {
      // (a) load + erase/write + raw scores
      #pragma unroll
      for (int pp = 0; pp < 2; ++pp) {
        int p = rowg + pp*32;
        int m = (ch<<6) + p;
        float4 v = mem4[m*16 + l16];
        float wm = sWwF[m];
        float4 nv;
        nv.x = v.x*(1.f - wm*er4.x) + wm*wv4.x;
        nv.y = v.y*(1.f - wm*er4.y) + wm*wv4.y;
        nv.z = v.z*(1.f - wm*er4.z) + wm*wv4.z;
        nv.w = v.w*(1.f - wm*er4.w) + wm*wv4.w;
        *(float4*)&chunk[p*68 + (l16<<2)] = nv;
        float d0 = nv.x*k0.x+nv.y*k0.y+nv.z*k0.z+nv.w*k0.w;
        float d1 = nv.x*k1.x+nv.y*k1.y+nv.z*k1.z+nv.w*k1.w;
        float d2 = nv.x*k2.x+nv.y*k2.y+nv.z*k2.z+nv.w*k2.w;
        float d3 = nv.x*k3.x+nv.y*k3.y+nv.z*k3.z+nv.w*k3.w;
        float q  = nv.x*nv.x+nv.y*nv.y+nv.z*nv.z+nv.w*nv.w;
        #pragma unroll
        for (int off=1; off<16; off<<=1){
          d0+=__shfl_xor(d0,off); d1+=__shfl_xor(d1,off);
          d2+=__shfl_xor(d2,off); d3+=__shfl_xor(d3,off);
          q +=__shfl_xor(q ,off);
        }
        if (l16==0){
          float inv = 1.f/(sqrtf(q)+EPSN);
          sE[      p] = d0*inv;
          sE[ 68 + p] = d1*inv;
          sE[136 + p] = d2*inv;
          sE[204 + p] = d3*inv;
        }
      }
      __syncthreads();
      // (b) per-head online softmax stats (wave h -> head h)
      if (wid < 4) {
        float v = sE[wid*68 + lane];
        float cm = v;
        #pragma unroll
        for (int off=1; off<64; off<<=1) cm = fmaxf(cm, __shfl_xor(cm,off));
        float om = sHm[wid];
        float nm = fmaxf(om, cm);
        float scl = expf(om - nm);
        float e = expf(v - nm);
        sE[wid*68 + lane] = e;
        float es = e;
        #pragma unroll
        for (int off=1; off<64; off<<=1) es += __shfl_xor(es,off);
        if (lane==0){
          sHs[wid] = sHs[wid]*scl + es;
          sHm[wid] = nm;
          sHsc[wid] = scl;
        }
      }
      __syncthreads();
      // (c) accumulate acc = acc*scale + sum_p e[rq][p]*mem[p][cq*4..+4)
      {
        float scl = sHsc[rq];
        acc.x*=scl; acc.y*=scl; acc.z*=scl; acc.w*=scl;
        #pragma unroll
        for (int pp=0; pp<8; ++pp){
          int p = (pg<<3) + pp;
          float e = sE[rq*68 + p];
          const float4 mv = *(const float4*)&chunk[p*68 + (cq<<2)];
          acc.x += e*mv.x; acc.y += e*mv.y; acc.z += e*mv.z; acc.w += e*mv.w;
        }
      }
      __syncthreads();
    }

    // ---- reduce 8 row-subgroup partials, normalize, write out ----
    float* red = (float*)sKeys + 2048;
    red[((rq*16+cq)*4 + 0)*8 + pg] = acc.x;
    red[((rq*16+cq)*4 + 1)*8 + pg] = acc.y;
    red[((rq*16+cq)*4 + 2)*8 + pg] = acc.z;
    red[((rq*16+cq)*4 + 3)*8 + pg] = acc.w;
    __syncthreads();
    if (tid < 256) {
      float s = 0.f;
      #pragma unroll
      for (int g=0; g<8; ++g) s += red[tid*8 + g];
      out[((size_t)b<<8) + tid] = s / sHs[tid>>6];
    }
  }
}

extern "C" void kernel_launch(void* const* d_in, const int* in_sizes, int n_in,
                              void* d_out, int out_size, void* d_ws, size_t ws_size,
                              hipStream_t stream) {
  const float* xi      = (const float*)d_in[0];
  const float* W       = (const float*)d_in[1];
  const float* gamma   = (const float*)d_in[2];
  const float* beta    = (const float*)d_in[3];
  const float* memory  = (const float*)d_in[4];
  const float* read_w  = (const float*)d_in[5];
  const float* write_w = (const float*)d_in[6];
  const float* usage   = (const float*)d_in[7];
  float* out = (float*)d_out;
  dnc_kernel<<<dim3(256), dim3(NT), 0, stream>>>(
      xi, W, gamma, beta, memory, read_w, write_w, usage, out);
}

// Round 2
// 152.001 us; speedup vs baseline: 1.3008x; 1.3008x over previous
//
#include <hip/hip_runtime.h>
#include <math.h>

#define MM    2048
#define CC    64
#define RH    4
#define NIF   461
#define INS   512
#define EPSN  1e-6f

typedef unsigned long long u64;

// ---- workspace layout (float offsets) ----
#define OFF_P    ((size_t)0)          // 256 x 512 params
#define OFF_U2   ((size_t)131072)     // 256 x 2048
#define OFF_MRW  ((size_t)655360)     // 256 x 2048
#define OFF_SC   ((size_t)1179648)    // 256 x 2048 raw write scores
#define OFF_WW   ((size_t)1703936)    // 256 x 2048 write weighting
#define OFF_PART ((size_t)2228224)    // 256 x 8 x 264 pass-B partials
// params per batch: [0..255] folded read keys, [256..319] folded write key,
// [320..383] erase, [384..447] write vec, [448..450] alloc gate, [451] write gate

// ================= K1: interface + gates + u2 + mean-read =================
__global__ __launch_bounds__(512) void k1_interface(
    const float* __restrict__ xi, const float* __restrict__ W,
    const float* __restrict__ gamma, const float* __restrict__ beta,
    const float* __restrict__ read_w, const float* __restrict__ write_w,
    const float* __restrict__ usage, float* __restrict__ ws)
{
  const int b = blockIdx.x, tid = threadIdx.x;
  const int lane = tid & 63, wid = tid >> 6;
  __shared__ __align__(16) float s_xi[512], s_itf[512], s_act[512];
  __shared__ float sRed[24];

  s_xi[tid] = xi[(size_t)b*INS + tid];
  __syncthreads();

  // itf = xi @ W^T, wave-cooperative per column
  {
    const float4 x0 = ((const float4*)s_xi)[lane*2];
    const float4 x1 = ((const float4*)s_xi)[lane*2+1];
    for (int col = wid; col < NIF; col += 8) {
      const float4* Wr = (const float4*)(W + (size_t)col*INS);
      float4 a0 = Wr[lane*2], a1 = Wr[lane*2+1];
      float p = a0.x*x0.x + a0.y*x0.y + a0.z*x0.z + a0.w*x0.w
              + a1.x*x1.x + a1.y*x1.y + a1.z*x1.z + a1.w*x1.w;
      #pragma unroll
      for (int off=1; off<64; off<<=1) p += __shfl_xor(p, off);
      if (lane==0) s_itf[col] = p;
    }
  }
  __syncthreads();

  // GroupNorm(1,C) + activations
  {
    float v = (tid < NIF) ? s_itf[tid] : 0.f;
    float s = v, q = v*v;
    #pragma unroll
    for (int off=1; off<64; off<<=1) { s += __shfl_xor(s,off); q += __shfl_xor(q,off); }
    if (lane==0){ sRed[wid] = s; sRed[8+wid] = q; }
    __syncthreads();
    if (tid==0){
      float ts=0.f, tq=0.f;
      for (int i=0;i<8;i++){ ts+=sRed[i]; tq+=sRed[8+i]; }
      float mean = ts/(float)NIF;
      float var  = tq/(float)NIF - mean*mean;
      sRed[16]=mean; sRed[17]=rsqrtf(var+1e-5f);
    }
    __syncthreads();
    float mean = sRed[16], rstd = sRed[17];
    if (tid < NIF) {
      float g = (s_itf[tid]-mean)*rstd*gamma[tid] + beta[tid];
      float a;
      if      (tid < 256) a = tanhf(g);
      else if (tid < 260) a = fmaxf(g,0.f) + log1pf(expf(-fabsf(g)));
      else if (tid < 324) a = tanhf(g);
      else if (tid ==324) a = fmaxf(g,0.f) + log1pf(expf(-fabsf(g)));
      else if (tid < 389) a = 1.f/(1.f+expf(-g));
      else if (tid < 453) a = tanhf(g);
      else if (tid < 457) a = 1.f/(1.f+expf(-g));
      else if (tid < 460) a = g;
      else                a = 1.f/(1.f+expf(-g));
      s_act[tid] = a;
    }
  }
  __syncthreads();

  // fold keys with norm*strength -> params
  float* P = ws + OFF_P + (size_t)b*512;
  if (wid < 4) {
    float t = s_act[wid*64 + lane];
    float q = t*t;
    #pragma unroll
    for (int off=1; off<64; off<<=1) q += __shfl_xor(q,off);
    P[wid*64+lane] = t * (s_act[256+wid] / (sqrtf(q) + EPSN));
  } else if (wid == 4) {
    float t = s_act[260+lane];
    float q = t*t;
    #pragma unroll
    for (int off=1; off<64; off<<=1) q += __shfl_xor(q,off);
    P[256+lane] = t * (s_act[324] / (sqrtf(q) + EPSN));
  } else if (wid == 5) {
    P[320+lane] = s_act[325+lane];
    P[384+lane] = s_act[389+lane];
  } else if (wid == 6 && lane == 0) {
    float a0=s_act[457], a1=s_act[458], a2=s_act[459];
    float mx = fmaxf(a0, fmaxf(a1,a2));
    float e0=expf(a0-mx), e1=expf(a1-mx), e2=expf(a2-mx);
    float is = 1.f/(e0+e1+e2);
    P[448]=e0*is; P[449]=e1*is; P[450]=e2*is; P[451]=s_act[460];
  }

  // u2 and mean-read weights (float4 over 2048)
  {
    const float4* us4 = (const float4*)(usage   + (size_t)b*MM);
    const float4* wr4 = (const float4*)(write_w + (size_t)b*MM);
    const float4* rw4 = (const float4*)(read_w  + (size_t)b*RH*MM);
    const float fg0=s_act[453], fg1=s_act[454], fg2=s_act[455], fg3=s_act[456];
    float4 u = us4[tid], w = wr4[tid];
    float4 r0 = rw4[tid], r1 = rw4[512+tid], r2 = rw4[1024+tid], r3 = rw4[1536+tid];
    float4 mr, u2o;
    mr.x = 0.25f*(r0.x+r1.x+r2.x+r3.x);
    mr.y = 0.25f*(r0.y+r1.y+r2.y+r3.y);
    mr.z = 0.25f*(r0.z+r1.z+r2.z+r3.z);
    mr.w = 0.25f*(r0.w+r1.w+r2.w+r3.w);
    #define U2C(comp)                                                           \
    { float uu  = u.comp + (1.f-u.comp)*w.comp;                                 \
      float psi = (1.f-fg0*r0.comp)*(1.f-fg1*r1.comp)*(1.f-fg2*r2.comp)*(1.f-fg3*r3.comp); \
      u2o.comp = 1e-6f + (1.f-1e-6f)*(uu*psi); }
    U2C(x) U2C(y) U2C(z) U2C(w)
    #undef U2C
    ((float4*)(ws + OFF_MRW + (size_t)b*MM))[tid] = mr;
    ((float4*)(ws + OFF_U2  + (size_t)b*MM))[tid] = u2o;
  }
}

// ================= K2: write-key cosine scores (8 slices/batch) ===========
__global__ __launch_bounds__(256) void k2_scores(
    const float* __restrict__ memory, float* __restrict__ ws)
{
  const int slice = blockIdx.x, b = blockIdx.y;
  const int tid = threadIdx.x, l16 = tid & 15, rowg = tid >> 4;
  const float* P = ws + OFF_P + (size_t)b*512;
  const float4 wk4 = ((const float4*)(P+256))[l16];
  const float4* mem4 = (const float4*)(memory + (size_t)b*MM*CC) + (size_t)slice*256*16;
  float* sc = ws + OFF_SC + (size_t)b*MM + slice*256;
  #pragma unroll 4
  for (int it = 0; it < 16; ++it) {
    int m = it*16 + rowg;
    float4 v = mem4[m*16 + l16];
    float d = v.x*wk4.x + v.y*wk4.y + v.z*wk4.z + v.w*wk4.w;
    float q = v.x*v.x + v.y*v.y + v.z*v.z + v.w*v.w;
    #pragma unroll
    for (int off=1; off<16; off<<=1){ d += __shfl_xor(d,off); q += __shfl_xor(q,off); }
    if (l16==0) sc[m] = d / (sqrtf(q)+EPSN);
  }
}

// ================= K3: sort + alloc + softmax + write weighting ===========
__global__ __launch_bounds__(1024) void k3_sortww(float* __restrict__ ws)
{
  const int b = blockIdx.x, tid = threadIdx.x;
  const int lane = tid & 63, wid = tid >> 6;   // 16 waves
  __shared__ __align__(16) u64   sKeys[2048];
  __shared__ __align__(16) float sA[2048], sB[2048];
  __shared__ float sRed[20];

  const float* u2p = ws + OFF_U2 + (size_t)b*MM;
  for (int i = tid; i < MM; i += 1024)
    sKeys[i] = ((u64)__float_as_uint(u2p[i])<<32) | (unsigned)i;

  // bitonic sort ascending, stable via packed index
  for (int k = 2; k <= MM; k <<= 1) {
    for (int j = k >> 1; j > 0; j >>= 1) {
      __syncthreads();
      for (int i = tid; i < MM; i += 1024) {
        int ixj = i ^ j;
        if (ixj > i) {
          u64 a = sKeys[i], c = sKeys[ixj];
          bool up = ((i & k) == 0);
          if ((a > c) == up) { sKeys[i] = c; sKeys[ixj] = a; }
        }
      }
    }
  }
  __syncthreads();

  // inclusive cumprod of sorted usage (Hillis-Steele)
  for (int i = tid; i < MM; i += 1024)
    sA[i] = __uint_as_float((unsigned)(sKeys[i]>>32));
  __syncthreads();
  float* src = sA; float* dst = sB;
  for (int d = 1; d < MM; d <<= 1) {
    for (int i = tid; i < MM; i += 1024) {
      float v = src[i];
      if (i >= d) v *= src[i-d];
      dst[i] = v;
    }
    __syncthreads();
    float* t = src; src = dst; dst = t;
  }
  // scatter alloc = (1-su)*excl_cumprod back to original index (into dst)
  for (int i = tid; i < MM; i += 1024) {
    u64 kk = sKeys[i];
    float su  = __uint_as_float((unsigned)(kk>>32));
    unsigned idx = (unsigned)(kk & 0xFFFFFFFFu);
    float cp = (i>0) ? src[i-1] : 1.f;
    dst[idx] = (1.f - su)*cp;
  }
  __syncthreads();
  float* allocBuf = dst;

  // softmax over write scores (reuse sKeys as float buffer)
  float* sF = (float*)sKeys;
  const float* scp = ws + OFF_SC + (size_t)b*MM;
  float lm = -INFINITY;
  for (int i = tid; i < MM; i += 1024) { float v = scp[i]; sF[i] = v; lm = fmaxf(lm, v); }
  #pragma unroll
  for (int off=1; off<64; off<<=1) lm = fmaxf(lm, __shfl_xor(lm,off));
  if (lane==0) sRed[wid] = lm;
  __syncthreads();
  if (tid==0){ float mx=sRed[0]; for(int i=1;i<16;i++) mx=fmaxf(mx,sRed[i]); sRed[16]=mx; }
  __syncthreads();
  float mx = sRed[16];
  float ls = 0.f;
  for (int i = tid; i < MM; i += 1024) { float e = expf(sF[i]-mx); sF[i]=e; ls += e; }
  #pragma unroll
  for (int off=1; off<64; off<<=1) ls += __shfl_xor(ls,off);
  if (lane==0) sRed[wid] = ls;
  __syncthreads();
  if (tid==0){ float s=0.f; for(int i=0;i<16;i++) s+=sRed[i]; sRed[17]=1.f/s; }
  __syncthreads();
  float inv = sRed[17];

  const float* P = ws + OFF_P + (size_t)b*512;
  const float ag0=P[448], ag1=P[449], ag2=P[450], wg=P[451];
  const float* mrwp = ws + OFF_MRW + (size_t)b*MM;
  float* wwp = ws + OFF_WW + (size_t)b*MM;
  for (int i = tid; i < MM; i += 1024)
    wwp[i] = wg*(ag0*mrwp[i] + ag1*allocBuf[i] + ag2*sF[i]*inv);
}

// ========== K4: erase/write + read scores + online-softmax partials =======
__global__ __launch_bounds__(256) void k4_passB(
    const float* __restrict__ memory, float* __restrict__ ws)
{
  const int slice = blockIdx.x, b = blockIdx.y;
  const int tid = threadIdx.x, l16 = tid & 15, rowg = tid >> 4;
  const int lane = tid & 63, wid = tid >> 6;       // 4 waves = 4 heads
  __shared__ __align__(16) float chunk[64*68];
  __shared__ __align__(16) float sE[4*68];
  __shared__ float sHm[4], sHs[4], sHsc[4];

  const float* P = ws + OFF_P + (size_t)b*512;
  const float4 er4 = ((const float4*)(P+320))[l16];
  const float4 wv4 = ((const float4*)(P+384))[l16];
  const float4 k0 = ((const float4*)P)[     l16];
  const float4 k1 = ((const float4*)P)[16 + l16];
  const float4 k2 = ((const float4*)P)[32 + l16];
  const float4 k3 = ((const float4*)P)[48 + l16];
  const float* wwp = ws + OFF_WW + (size_t)b*MM + slice*256;
  const float4* mem4 = (const float4*)(memory + (size_t)b*MM*CC) + (size_t)slice*256*16;

  if (tid < 4){ sHm[tid] = -INFINITY; sHs[tid] = 0.f; }
  __syncthreads();
  float acc = 0.f;   // head = wid, col = lane

  for (int ch = 0; ch < 4; ++ch) {
    #pragma unroll
    for (int pp = 0; pp < 4; ++pp) {
      int p = pp*16 + rowg;          // 0..63 local row
      int m = ch*64 + p;             // row within slice
      float4 v = mem4[m*16 + l16];
      float wm = wwp[m];
      float4 nv;
      nv.x = v.x*(1.f - wm*er4.x) + wm*wv4.x;
      nv.y = v.y*(1.f - wm*er4.y) + wm*wv4.y;
      nv.z = v.z*(1.f - wm*er4.z) + wm*wv4.z;
      nv.w = v.w*(1.f - wm*er4.w) + wm*wv4.w;
      *(float4*)&chunk[p*68 + (l16<<2)] = nv;
      float d0 = nv.x*k0.x+nv.y*k0.y+nv.z*k0.z+nv.w*k0.w;
      float d1 = nv.x*k1.x+nv.y*k1.y+nv.z*k1.z+nv.w*k1.w;
      float d2 = nv.x*k2.x+nv.y*k2.y+nv.z*k2.z+nv.w*k2.w;
      float d3 = nv.x*k3.x+nv.y*k3.y+nv.z*k3.z+nv.w*k3.w;
      float q  = nv.x*nv.x+nv.y*nv.y+nv.z*nv.z+nv.w*nv.w;
      #pragma unroll
      for (int off=1; off<16; off<<=1){
        d0+=__shfl_xor(d0,off); d1+=__shfl_xor(d1,off);
        d2+=__shfl_xor(d2,off); d3+=__shfl_xor(d3,off);
        q +=__shfl_xor(q ,off);
      }
      if (l16==0){
        float inv = 1.f/(sqrtf(q)+EPSN);
        sE[      p] = d0*inv;
        sE[ 68 + p] = d1*inv;
        sE[136 + p] = d2*inv;
        sE[204 + p] = d3*inv;
      }
    }
    __syncthreads();
    // per-head online softmax stats (wave w = head w)
    {
      float v = sE[wid*68 + lane];
      float cm = v;
      #pragma unroll
      for (int off=1; off<64; off<<=1) cm = fmaxf(cm, __shfl_xor(cm,off));
      float om = sHm[wid];
      float nm = fmaxf(om, cm);
      float scl = expf(om - nm);
      float e = expf(v - nm);
      sE[wid*68 + lane] = e;
      float es = e;
      #pragma unroll
      for (int off=1; off<64; off<<=1) es += __shfl_xor(es,off);
      if (lane==0){
        sHs[wid] = sHs[wid]*scl + es;
        sHm[wid] = nm;
        sHsc[wid] = scl;
      }
    }
    __syncthreads();
    // acc = acc*scale + sum_p e[head][p]*chunk[p][col]
    {
      float scl = sHsc[wid];
      acc *= scl;
      #pragma unroll 8
      for (int p = 0; p < 64; ++p)
        acc += sE[wid*68 + p] * chunk[p*68 + lane];
    }
    __syncthreads();
  }

  float* part = ws + OFF_PART + ((size_t)(b*8 + slice))*264;
  part[wid*66 + 2 + lane] = acc;
  if (lane==0){ part[wid*66 + 0] = sHm[wid]; part[wid*66 + 1] = sHs[wid]; }
}

// ================= K5: combine slice partials, normalize ==================
__global__ __launch_bounds__(256) void k5_combine(
    const float* __restrict__ ws, float* __restrict__ out)
{
  const int b = blockIdx.x, tid = threadIdx.x;
  const int head = tid >> 6, c = tid & 63;
  const float* part = ws + OFF_PART + (size_t)b*8*264;
  float M = -INFINITY;
  #pragma unroll
  for (int s = 0; s < 8; ++s) M = fmaxf(M, part[s*264 + head*66]);
  float S = 0.f, A = 0.f;
  #pragma unroll
  for (int s = 0; s < 8; ++s) {
    float w = expf(part[s*264 + head*66] - M);
    S += w * part[s*264 + head*66 + 1];
    A += w * part[s*264 + head*66 + 2 + c];
  }
  out[((size_t)b<<8) + head*64 + c] = A / S;
}

extern "C" void kernel_launch(void* const* d_in, const int* in_sizes, int n_in,
                              void* d_out, int out_size, void* d_ws, size_t ws_size,
                              hipStream_t stream) {
  const float* xi      = (const float*)d_in[0];
  const float* W       = (const float*)d_in[1];
  const float* gamma   = (const float*)d_in[2];
  const float* beta    = (const float*)d_in[3];
  const float* memory  = (const float*)d_in[4];
  const float* read_w  = (const float*)d_in[5];
  const float* write_w = (const float*)d_in[6];
  const float* usage   = (const float*)d_in[7];
  float* ws  = (float*)d_ws;
  float* out = (float*)d_out;

  k1_interface<<<dim3(256), dim3(512), 0, stream>>>(xi, W, gamma, beta, read_w, write_w, usage, ws);
  k2_scores  <<<dim3(8,256), dim3(256), 0, stream>>>(memory, ws);
  k3_sortww  <<<dim3(256), dim3(1024), 0, stream>>>(ws);
  k4_passB   <<<dim3(8,256), dim3(256), 0, stream>>>(memory, ws);
  k5_combine <<<dim3(256), dim3(256), 0, stream>>>(ws, out);
}

// Round 3
// 132.296 us; speedup vs baseline: 1.4946x; 1.1489x over previous
//
#include <hip/hip_runtime.h>
#include <math.h>

#define MM    2048
#define CC    64
#define RH    4
#define NIF   461
#define INS   512
#define EPSN  1e-6f

typedef unsigned long long u64;

// ---- workspace layout (float offsets) ----
#define OFF_P     ((size_t)0)          // 256 x 512 params
#define OFF_U2    ((size_t)131072)     // 256 x 2048
#define OFF_MRW   ((size_t)655360)     // 256 x 2048
#define OFF_SC    ((size_t)1179648)    // 256 x 2048 raw write scores
#define OFF_ALLOC ((size_t)1703936)    // 256 x 2048 allocation weights
#define OFF_WW    ((size_t)2228224)    // 256 x 2048 write weighting
#define OFF_PART  ((size_t)2752512)    // 256 x 8 x 4 x 64 pass-B acc partials
#define OFF_PSTAT ((size_t)3276800)    // 256 x 8 x 4 x 2 {m,s}
// params per batch: [0..255] folded read keys, [256..319] folded write key,
// [320..383] erase, [384..447] write vec, [448..450] alloc gate, [451] write gate

// ================= K1: interface + gates + u2 + mean-read =================
__global__ __launch_bounds__(512) void k1_interface(
    const float* __restrict__ xi, const float* __restrict__ W,
    const float* __restrict__ gamma, const float* __restrict__ beta,
    const float* __restrict__ read_w, const float* __restrict__ write_w,
    const float* __restrict__ usage, float* __restrict__ ws)
{
  const int b = blockIdx.x, tid = threadIdx.x;
  const int lane = tid & 63, wid = tid >> 6;
  __shared__ __align__(16) float s_xi[512], s_itf[512], s_act[512];
  __shared__ float sRed[24];

  s_xi[tid] = xi[(size_t)b*INS + tid];
  __syncthreads();

  {
    const float4 x0 = ((const float4*)s_xi)[lane*2];
    const float4 x1 = ((const float4*)s_xi)[lane*2+1];
    for (int col = wid; col < NIF; col += 8) {
      const float4* Wr = (const float4*)(W + (size_t)col*INS);
      float4 a0 = Wr[lane*2], a1 = Wr[lane*2+1];
      float p = a0.x*x0.x + a0.y*x0.y + a0.z*x0.z + a0.w*x0.w
              + a1.x*x1.x + a1.y*x1.y + a1.z*x1.z + a1.w*x1.w;
      #pragma unroll
      for (int off=1; off<64; off<<=1) p += __shfl_xor(p, off);
      if (lane==0) s_itf[col] = p;
    }
  }
  __syncthreads();

  {
    float v = (tid < NIF) ? s_itf[tid] : 0.f;
    float s = v, q = v*v;
    #pragma unroll
    for (int off=1; off<64; off<<=1) { s += __shfl_xor(s,off); q += __shfl_xor(q,off); }
    if (lane==0){ sRed[wid] = s; sRed[8+wid] = q; }
    __syncthreads();
    if (tid==0){
      float ts=0.f, tq=0.f;
      for (int i=0;i<8;i++){ ts+=sRed[i]; tq+=sRed[8+i]; }
      float mean = ts/(float)NIF;
      float var  = tq/(float)NIF - mean*mean;
      sRed[16]=mean; sRed[17]=rsqrtf(var+1e-5f);
    }
    __syncthreads();
    float mean = sRed[16], rstd = sRed[17];
    if (tid < NIF) {
      float g = (s_itf[tid]-mean)*rstd*gamma[tid] + beta[tid];
      float a;
      if      (tid < 256) a = tanhf(g);
      else if (tid < 260) a = fmaxf(g,0.f) + log1pf(expf(-fabsf(g)));
      else if (tid < 324) a = tanhf(g);
      else if (tid ==324) a = fmaxf(g,0.f) + log1pf(expf(-fabsf(g)));
      else if (tid < 389) a = 1.f/(1.f+expf(-g));
      else if (tid < 453) a = tanhf(g);
      else if (tid < 457) a = 1.f/(1.f+expf(-g));
      else if (tid < 460) a = g;
      else                a = 1.f/(1.f+expf(-g));
      s_act[tid] = a;
    }
  }
  __syncthreads();

  float* P = ws + OFF_P + (size_t)b*512;
  if (wid < 4) {
    float t = s_act[wid*64 + lane];
    float q = t*t;
    #pragma unroll
    for (int off=1; off<64; off<<=1) q += __shfl_xor(q,off);
    P[wid*64+lane] = t * (s_act[256+wid] / (sqrtf(q) + EPSN));
  } else if (wid == 4) {
    float t = s_act[260+lane];
    float q = t*t;
    #pragma unroll
    for (int off=1; off<64; off<<=1) q += __shfl_xor(q,off);
    P[256+lane] = t * (s_act[324] / (sqrtf(q) + EPSN));
  } else if (wid == 5) {
    P[320+lane] = s_act[325+lane];
    P[384+lane] = s_act[389+lane];
  } else if (wid == 6 && lane == 0) {
    float a0=s_act[457], a1=s_act[458], a2=s_act[459];
    float mx = fmaxf(a0, fmaxf(a1,a2));
    float e0=expf(a0-mx), e1=expf(a1-mx), e2=expf(a2-mx);
    float is = 1.f/(e0+e1+e2);
    P[448]=e0*is; P[449]=e1*is; P[450]=e2*is; P[451]=s_act[460];
  }

  {
    const float4* us4 = (const float4*)(usage   + (size_t)b*MM);
    const float4* wr4 = (const float4*)(write_w + (size_t)b*MM);
    const float4* rw4 = (const float4*)(read_w  + (size_t)b*RH*MM);
    const float fg0=s_act[453], fg1=s_act[454], fg2=s_act[455], fg3=s_act[456];
    float4 u = us4[tid], w = wr4[tid];
    float4 r0 = rw4[tid], r1 = rw4[512+tid], r2 = rw4[1024+tid], r3 = rw4[1536+tid];
    float4 mr, u2o;
    mr.x = 0.25f*(r0.x+r1.x+r2.x+r3.x);
    mr.y = 0.25f*(r0.y+r1.y+r2.y+r3.y);
    mr.z = 0.25f*(r0.z+r1.z+r2.z+r3.z);
    mr.w = 0.25f*(r0.w+r1.w+r2.w+r3.w);
    #define U2C(comp)                                                           \
    { float uu  = u.comp + (1.f-u.comp)*w.comp;                                 \
      float psi = (1.f-fg0*r0.comp)*(1.f-fg1*r1.comp)*(1.f-fg2*r2.comp)*(1.f-fg3*r3.comp); \
      u2o.comp = 1e-6f + (1.f-1e-6f)*(uu*psi); }
    U2C(x) U2C(y) U2C(z) U2C(w)
    #undef U2C
    ((float4*)(ws + OFF_MRW + (size_t)b*MM))[tid] = mr;
    ((float4*)(ws + OFF_U2  + (size_t)b*MM))[tid] = u2o;
  }
}

// ====== K2: heterogeneous — blocks [0,256): sort+alloc; [256,2304): scores ======
__global__ __launch_bounds__(256) void k2_fused(
    const float* __restrict__ memory, float* __restrict__ ws)
{
  __shared__ __align__(16) u64 sKeys[2048];   // sort path only (16KB)
  __shared__ float sT[260];
  const int tid = threadIdx.x;

  if (blockIdx.x < 256) {
    // ---------------- sort + allocation path ----------------
    const int b = blockIdx.x;
    const int lane = tid & 63, w = tid >> 6;
    const float* u2p = ws + OFF_U2 + (size_t)b*MM;
    for (int i = tid; i < MM; i += 256)
      sKeys[i] = ((u64)__float_as_uint(u2p[i])<<32) | (unsigned)i;
    __syncthreads();

    // bitonic sort ascending (stable via packed index)
    for (int k = 2; k <= MM; k <<= 1) {
      for (int j = k >> 1; j > 0; j >>= 1) {
        #pragma unroll 4
        for (int c = tid; c < MM/2; c += 256) {
          int i   = ((c & ~(j-1)) << 1) | (c & (j-1));
          int ixj = i | j;
          u64 a = sKeys[i], d = sKeys[ixj];
          bool up = ((i & k) == 0);
          if ((a > d) == up) { sKeys[i] = d; sKeys[ixj] = a; }
        }
        __syncthreads();
      }
    }

    // cumprod: thread t owns sorted elements [8t, 8t+8)
    float p[8];
    {
      float run = 1.f;
      #pragma unroll
      for (int e = 0; e < 8; ++e) {
        float su = __uint_as_float((unsigned)(sKeys[tid*8+e]>>32));
        run *= su; p[e] = run;
      }
      sT[tid] = run;
    }
    __syncthreads();
    float v = sT[tid];
    float incl = v;
    #pragma unroll
    for (int off=1; off<64; off<<=1) {
      float n = __shfl_up(incl, off);
      if (lane >= off) incl *= n;
    }
    float excl = __shfl_up(incl, 1);
    if (lane == 0) excl = 1.f;
    if (lane == 63) sT[256 + w] = incl;
    __syncthreads();
    float base = 1.f;
    for (int ww2 = 0; ww2 < w; ++ww2) base *= sT[256 + ww2];
    float E = base * excl;     // exclusive product before this thread's span

    float* allocp = ws + OFF_ALLOC + (size_t)b*MM;
    #pragma unroll
    for (int e = 0; e < 8; ++e) {
      u64 kk = sKeys[tid*8+e];
      float su = __uint_as_float((unsigned)(kk>>32));
      unsigned idx = (unsigned)(kk & 0xFFFFFFFFu);
      float cp = E * (e ? p[e-1] : 1.f);
      allocp[idx] = (1.f - su) * cp;
    }
  } else {
    // ---------------- write-key cosine score path ----------------
    const int f = blockIdx.x - 256;
    const int b = f >> 3, slice = f & 7;
    const int l16 = tid & 15, rowg = tid >> 4;
    const float* P = ws + OFF_P + (size_t)b*512;
    const float4 wk4 = ((const float4*)(P+256))[l16];
    const float4* mem4 = (const float4*)(memory + (size_t)b*MM*CC) + (size_t)slice*256*16;
    float* sc = ws + OFF_SC + (size_t)b*MM + slice*256;
    #pragma unroll 4
    for (int it = 0; it < 16; ++it) {
      int m = it*16 + rowg;
      float4 vv = mem4[m*16 + l16];
      float d = vv.x*wk4.x + vv.y*wk4.y + vv.z*wk4.z + vv.w*wk4.w;
      float q = vv.x*vv.x + vv.y*vv.y + vv.z*vv.z + vv.w*vv.w;
      #pragma unroll
      for (int off=1; off<16; off<<=1){ d += __shfl_xor(d,off); q += __shfl_xor(q,off); }
      if (l16==0) sc[m] = d / (sqrtf(q)+EPSN);
    }
  }
}

// ============ K3: softmax over write scores + write weighting =============
__global__ __launch_bounds__(256) void k3_ww(float* __restrict__ ws)
{
  const int b = blockIdx.x, tid = threadIdx.x;
  const int lane = tid & 63, w = tid >> 6;
  __shared__ float sR[8];
  const float4* sc4 = (const float4*)(ws + OFF_SC + (size_t)b*MM);
  float4 v0 = sc4[tid*2], v1 = sc4[tid*2+1];
  float m = fmaxf(fmaxf(fmaxf(v0.x,v0.y),fmaxf(v0.z,v0.w)),
                  fmaxf(fmaxf(v1.x,v1.y),fmaxf(v1.z,v1.w)));
  #pragma unroll
  for (int off=1; off<64; off<<=1) m = fmaxf(m, __shfl_xor(m,off));
  if (lane==0) sR[w] = m;
  __syncthreads();
  m = fmaxf(fmaxf(sR[0],sR[1]), fmaxf(sR[2],sR[3]));
  float e0=expf(v0.x-m), e1=expf(v0.y-m), e2=expf(v0.z-m), e3=expf(v0.w-m);
  float e4=expf(v1.x-m), e5=expf(v1.y-m), e6=expf(v1.z-m), e7=expf(v1.w-m);
  float s = e0+e1+e2+e3+e4+e5+e6+e7;
  #pragma unroll
  for (int off=1; off<64; off<<=1) s += __shfl_xor(s,off);
  if (lane==0) sR[4+w] = s;
  __syncthreads();
  float inv = 1.f/(sR[4]+sR[5]+sR[6]+sR[7]);

  const float* P = ws + OFF_P + (size_t)b*512;
  const float ag0=P[448], ag1=P[449], ag2=P[450], wg=P[451];
  const float4* mr4 = (const float4*)(ws + OFF_MRW   + (size_t)b*MM);
  const float4* al4 = (const float4*)(ws + OFF_ALLOC + (size_t)b*MM);
  float4* ww4 = (float4*)(ws + OFF_WW + (size_t)b*MM);
  float4 mra = mr4[tid*2], mrb = mr4[tid*2+1];
  float4 ala = al4[tid*2], alb = al4[tid*2+1];
  float4 oa, ob;
  oa.x = wg*(ag0*mra.x + ag1*ala.x + ag2*e0*inv);
  oa.y = wg*(ag0*mra.y + ag1*ala.y + ag2*e1*inv);
  oa.z = wg*(ag0*mra.z + ag1*ala.z + ag2*e2*inv);
  oa.w = wg*(ag0*mra.w + ag1*ala.w + ag2*e3*inv);
  ob.x = wg*(ag0*mrb.x + ag1*alb.x + ag2*e4*inv);
  ob.y = wg*(ag0*mrb.y + ag1*alb.y + ag2*e5*inv);
  ob.z = wg*(ag0*mrb.z + ag1*alb.z + ag2*e6*inv);
  ob.w = wg*(ag0*mrb.w + ag1*alb.w + ag2*e7*inv);
  ww4[tid*2] = oa; ww4[tid*2+1] = ob;
}

// ========== K4: erase/write + read scores + online-softmax partials =======
__global__ __launch_bounds__(256) void k4_passB(
    const float* __restrict__ memory, float* __restrict__ ws)
{
  const int slice = blockIdx.x, b = blockIdx.y;
  const int tid = threadIdx.x, l16 = tid & 15, rowg = tid >> 4;
  const int lane = tid & 63, wid = tid >> 6;       // 4 waves = 4 heads
  __shared__ __align__(16) float chunk[64*68];
  __shared__ __align__(16) float sE[4*68];
  __shared__ float sHm[4], sHs[4], sHsc[4];

  const float* P = ws + OFF_P + (size_t)b*512;
  const float4 er4 = ((const float4*)(P+320))[l16];
  const float4 wv4 = ((const float4*)(P+384))[l16];
  const float4 k0 = ((const float4*)P)[     l16];
  const float4 k1 = ((const float4*)P)[16 + l16];
  const float4 k2 = ((const float4*)P)[32 + l16];
  const float4 k3 = ((const float4*)P)[48 + l16];
  const float* wwp = ws + OFF_WW + (size_t)b*MM + slice*256;
  const float4* mem4 = (const float4*)(memory + (size_t)b*MM*CC) + (size_t)slice*256*16;

  if (tid < 4){ sHm[tid] = -INFINITY; sHs[tid] = 0.f; }
  __syncthreads();
  const int q = lane & 15, ps = lane >> 4;
  float4 acc; acc.x=acc.y=acc.z=acc.w=0.f;   // (head=wid, colquad=q, p-range=ps)

  for (int ch = 0; ch < 4; ++ch) {
    #pragma unroll
    for (int pp = 0; pp < 4; ++pp) {
      int p = pp*16 + rowg;
      int m = ch*64 + p;
      float4 v = mem4[m*16 + l16];
      float wm = wwp[m];
      float4 nv;
      nv.x = v.x*(1.f - wm*er4.x) + wm*wv4.x;
      nv.y = v.y*(1.f - wm*er4.y) + wm*wv4.y;
      nv.z = v.z*(1.f - wm*er4.z) + wm*wv4.z;
      nv.w = v.w*(1.f - wm*er4.w) + wm*wv4.w;
      *(float4*)&chunk[p*68 + (l16<<2)] = nv;
      float d0 = nv.x*k0.x+nv.y*k0.y+nv.z*k0.z+nv.w*k0.w;
      float d1 = nv.x*k1.x+nv.y*k1.y+nv.z*k1.z+nv.w*k1.w;
      float d2 = nv.x*k2.x+nv.y*k2.y+nv.z*k2.z+nv.w*k2.w;
      float d3 = nv.x*k3.x+nv.y*k3.y+nv.z*k3.z+nv.w*k3.w;
      float qq = nv.x*nv.x+nv.y*nv.y+nv.z*nv.z+nv.w*nv.w;
      #pragma unroll
      for (int off=1; off<16; off<<=1){
        d0+=__shfl_xor(d0,off); d1+=__shfl_xor(d1,off);
        d2+=__shfl_xor(d2,off); d3+=__shfl_xor(d3,off);
        qq+=__shfl_xor(qq,off);
      }
      if (l16==0){
        float inv = 1.f/(sqrtf(qq)+EPSN);
        sE[      p] = d0*inv;
        sE[ 68 + p] = d1*inv;
        sE[136 + p] = d2*inv;
        sE[204 + p] = d3*inv;
      }
    }
    __syncthreads();
    // per-head online softmax stats (wave = head)
    {
      float v = sE[wid*68 + lane];
      float cm = v;
      #pragma unroll
      for (int off=1; off<64; off<<=1) cm = fmaxf(cm, __shfl_xor(cm,off));
      float om = sHm[wid];
      float nm = fmaxf(om, cm);
      float scl = expf(om - nm);
      float e = expf(v - nm);
      sE[wid*68 + lane] = e;
      float es = e;
      #pragma unroll
      for (int off=1; off<64; off<<=1) es += __shfl_xor(es,off);
      if (lane==0){
        sHs[wid] = sHs[wid]*scl + es;
        sHm[wid] = nm;
        sHsc[wid] = scl;
      }
    }
    __syncthreads();
    // acc(head,q) partial over p = ps*16..ps*16+15, float4 LDS reads
    {
      float scl = sHsc[wid];
      acc.x*=scl; acc.y*=scl; acc.z*=scl; acc.w*=scl;
      #pragma unroll
      for (int pp = 0; pp < 16; ++pp) {
        int p = ps*16 + pp;
        float e = sE[wid*68 + p];
        const float4 mv = *(const float4*)&chunk[p*68 + (q<<2)];
        acc.x += e*mv.x; acc.y += e*mv.y; acc.z += e*mv.z; acc.w += e*mv.w;
      }
    }
    __syncthreads();
  }

  // reduce the 4 p-range partials (lanes ps=0..3 share (head,q))
  #pragma unroll
  for (int off=16; off<64; off<<=1) {
    acc.x += __shfl_xor(acc.x, off);
    acc.y += __shfl_xor(acc.y, off);
    acc.z += __shfl_xor(acc.z, off);
    acc.w += __shfl_xor(acc.w, off);
  }
  if (ps == 0) {
    float* pacc = ws + OFF_PART + ((((size_t)b*8 + slice)*4 + wid)<<6);
    *(float4*)&pacc[q<<2] = acc;
  }
  if (lane == 0) {
    float* pst = ws + OFF_PSTAT + (((size_t)b*8 + slice)*4 + wid)*2;
    pst[0] = sHm[wid]; pst[1] = sHs[wid];
  }
}

// ================= K5: combine slice partials, normalize ==================
__global__ __launch_bounds__(256) void k5_combine(
    const float* __restrict__ ws, float* __restrict__ out)
{
  const int b = blockIdx.x, tid = threadIdx.x;
  const int head = tid >> 6, c = tid & 63;
  float M = -INFINITY;
  #pragma unroll
  for (int s = 0; s < 8; ++s)
    M = fmaxf(M, ws[OFF_PSTAT + (((size_t)b*8 + s)*4 + head)*2]);
  float S = 0.f, A = 0.f;
  #pragma unroll
  for (int s = 0; s < 8; ++s) {
    const float* pst = ws + OFF_PSTAT + (((size_t)b*8 + s)*4 + head)*2;
    float w = expf(pst[0] - M);
    S += w * pst[1];
    A += w * ws[OFF_PART + ((((size_t)b*8 + s)*4 + head)<<6) + c];
  }
  out[((size_t)b<<8) + head*64 + c] = A / S;
}

extern "C" void kernel_launch(void* const* d_in, const int* in_sizes, int n_in,
                              void* d_out, int out_size, void* d_ws, size_t ws_size,
                              hipStream_t stream) {
  const float* xi      = (const float*)d_in[0];
  const float* W       = (const float*)d_in[1];
  const float* gamma   = (const float*)d_in[2];
  const float* beta    = (const float*)d_in[3];
  const float* memory  = (const float*)d_in[4];
  const float* read_w  = (const float*)d_in[5];
  const float* write_w = (const float*)d_in[6];
  const float* usage   = (const float*)d_in[7];
  float* ws  = (float*)d_ws;
  float* out = (float*)d_out;

  k1_interface<<<dim3(256), dim3(512), 0, stream>>>(xi, W, gamma, beta, read_w, write_w, usage, ws);
  k2_fused   <<<dim3(2304), dim3(256), 0, stream>>>(memory, ws);
  k3_ww      <<<dim3(256), dim3(256), 0, stream>>>(ws);
  k4_passB   <<<dim3(8,256), dim3(256), 0, stream>>>(memory, ws);
  k5_combine <<<dim3(256), dim3(256), 0, stream>>>(ws, out);
}